// Round 5
// baseline (480.835 us; speedup 1.0000x reference)
//
#include <hip/hip_runtime.h>

// SpatialAttention: B=32, C=512, D=64, N=1024 (H=W=32)
#define BB 32
#define CC 512
#define DD 64
#define NN 1024

typedef float4 f4;
typedef __attribute__((ext_vector_type(8))) short bf16x8;     // 8 bf16 = 4 VGPRs (MFMA A/B frag)
typedef __attribute__((ext_vector_type(4))) float f32x4;      // MFMA C/D frag
typedef __attribute__((ext_vector_type(4))) unsigned short us4;
typedef __attribute__((ext_vector_type(8))) unsigned short us8;

__device__ inline unsigned short bf16rn(float f) {
  union { float f; unsigned u; } v; v.f = f;
  unsigned r = v.u + 0x7fff + ((v.u >> 16) & 1);   // round-to-nearest-even
  return (unsigned short)(r >> 16);
}

__device__ inline void gl_lds16(const void* g, void* l) {
  // async global->LDS, 16B/lane; LDS dest = wave-uniform base + lane*16
  __builtin_amdgcn_global_load_lds(
      (const __attribute__((address_space(1))) unsigned int*)g,
      (__attribute__((address_space(3))) unsigned int*)l, 16, 0, 0);
}

// ---- shared GEMM core: C[128m x 128n] += A[M][K] * Bt[N][K]^T, bf16, BK=64 ----
// LDS tiles: 128 rows x 64 k-elems, XOR-swizzled: slot s of row r holds global
// k-group (s ^ (r&7)); 16B groups. Conflict-free (verified r4: SQ_LDS_BANK_CONFLICT=0).
template <int KDIM>
__device__ inline void gemm_core(const unsigned short* __restrict__ A,
                                 const unsigned short* __restrict__ Bt,
                                 int m0, int n0, int tid,
                                 unsigned short* sA, unsigned short* sB,
                                 f32x4 acc[4][4]) {
  const int wave = tid >> 6, lane = tid & 63;
  const int wm = (wave & 1) * 64, wn = (wave >> 1) * 64;
  const int fm = lane & 15;           // fragment row (m or n)
  const int kq = lane >> 4;           // fragment k-group (0..3) within 32-k window
  const int srow = lane >> 3;         // staging: row within 8-row slab (0..7)
  const int sg   = (lane & 7) ^ srow; // staging: global k-group (swizzled)

  for (int k0 = 0; k0 < KDIM; k0 += 64) {
#pragma unroll
    for (int t = 0; t < 4; ++t) {
      const int R = wave * 32 + t * 8;     // row base of this 8-row slab
      gl_lds16(A  + (size_t)(m0 + R + srow) * KDIM + k0 + sg * 8, sA + R * 64);
      gl_lds16(Bt + (size_t)(n0 + R + srow) * KDIM + k0 + sg * 8, sB + R * 64);
    }
    __syncthreads();
#pragma unroll
    for (int ks = 0; ks < 2; ++ks) {
      bf16x8 af[4], bfr[4];
#pragma unroll
      for (int i = 0; i < 4; ++i) {
        const int ra = wm + i * 16 + fm;
        const int rb = wn + i * 16 + fm;
        af[i]  = *(const bf16x8*)(sA + ra * 64 + ((ks * 4 + kq) ^ (ra & 7)) * 8);
        bfr[i] = *(const bf16x8*)(sB + rb * 64 + ((ks * 4 + kq) ^ (rb & 7)) * 8);
      }
#pragma unroll
      for (int i = 0; i < 4; ++i)
#pragma unroll
        for (int j = 0; j < 4; ++j)
          acc[i][j] = __builtin_amdgcn_mfma_f32_16x16x32_bf16(af[i], bfr[j], acc[i][j], 0, 0, 0);
    }
    __syncthreads();
  }
}

// ---------------- prep: weights -> bf16 ----------------
__global__ __launch_bounds__(256) void prep_w(
    const float* __restrict__ qw, const float* __restrict__ kw, const float* __restrict__ vw,
    const float* __restrict__ qb, const float* __restrict__ kb, const float* __restrict__ vb,
    const float* __restrict__ ow,
    unsigned short* __restrict__ wcat, unsigned short* __restrict__ owb,
    float* __restrict__ bcat) {
  int idx = blockIdx.x * 256 + threadIdx.x;
  if (idx < 640 * 512) {
    int row = idx >> 9;
    float v = (row < 64) ? qw[idx] : (row < 128) ? kw[idx - 64 * 512] : vw[idx - 128 * 512];
    wcat[idx] = bf16rn(v);
    if (idx < 640) bcat[idx] = (idx < 64) ? qb[idx] : (idx < 128) ? kb[idx - 64] : vb[idx - 128];
  } else {
    int j = idx - 640 * 512;
    owb[j] = bf16rn(ow[j]);
  }
}

// ---------------- prep: A[b][i][c] = bf16(x[b][c][i] + pos[c][i]) ----------------
__global__ __launch_bounds__(256) void prep_x(const float* __restrict__ x,
                                              const float* __restrict__ pos,
                                              unsigned short* __restrict__ A) {
  __shared__ float t[64][65];
  const int b = blockIdx.z, i0 = blockIdx.x * 64, c0 = blockIdx.y * 64;
  const int tid = threadIdx.x;
  const int ci = tid >> 4, il = (tid & 15) * 4;
  const float* xb = x + (size_t)b * CC * NN;
#pragma unroll
  for (int r = 0; r < 4; ++r) {
    int cl = r * 16 + ci;
    f4 xv = *(const f4*)(xb  + (size_t)(c0 + cl) * NN + i0 + il);
    f4 pv = *(const f4*)(pos + (size_t)(c0 + cl) * NN + i0 + il);
    t[cl][il + 0] = xv.x + pv.x;
    t[cl][il + 1] = xv.y + pv.y;
    t[cl][il + 2] = xv.z + pv.z;
    t[cl][il + 3] = xv.w + pv.w;
  }
  __syncthreads();
  const int iw = tid >> 2, cw = (tid & 3) * 16;
  unsigned short* dst = A + ((size_t)b * NN + i0 + iw) * CC + c0 + cw;
  us8 p0, p1;
#pragma unroll
  for (int j = 0; j < 8; ++j) p0[j] = bf16rn(t[cw + j][iw]);
#pragma unroll
  for (int j = 0; j < 8; ++j) p1[j] = bf16rn(t[cw + 8 + j][iw]);
  *(us8*)dst = p0;
  *(us8*)(dst + 8) = p1;
}

// ---------------- QKV projection GEMM ----------------
__global__ __launch_bounds__(256) void proj_gemm(
    const unsigned short* __restrict__ A, const unsigned short* __restrict__ wcat,
    const float* __restrict__ bcat,
    unsigned short* __restrict__ qo, unsigned short* __restrict__ ko,
    unsigned short* __restrict__ vto) {
  __shared__ unsigned short sA[8192], sB[8192];
  const int b = blockIdx.z, m0 = blockIdx.x * 128, n0 = blockIdx.y * 128;
  const int tid = threadIdx.x, wave = tid >> 6, lane = tid & 63;
  f32x4 acc[4][4];
#pragma unroll
  for (int i = 0; i < 4; ++i)
#pragma unroll
    for (int j = 0; j < 4; ++j) acc[i][j] = (f32x4)(0.0f);

  gemm_core<512>(A + (size_t)b * NN * CC, wcat, m0, n0, tid, sA, sB, acc);

  const int wm = (wave & 1) * 64, wn = (wave >> 1) * 64;
#pragma unroll
  for (int i = 0; i < 4; ++i)
#pragma unroll
    for (int j = 0; j < 4; ++j) {
      int col  = n0 + wn + j * 16 + (lane & 15);
      int rowb = m0 + wm + i * 16 + (lane >> 4) * 4;
      float bias = bcat[col];
      if (col < 64) {
#pragma unroll
        for (int r = 0; r < 4; ++r)
          qo[((size_t)b * NN + rowb + r) * DD + col] = bf16rn(acc[i][j][r] + bias);
      } else if (col < 128) {
#pragma unroll
        for (int r = 0; r < 4; ++r)
          ko[((size_t)b * NN + rowb + r) * DD + col - 64] = bf16rn(acc[i][j][r] + bias);
      } else {
        int c = col - 128;
        us4 pk;
#pragma unroll
        for (int r = 0; r < 4; ++r) pk[r] = bf16rn(acc[i][j][r] + bias);
        *(us4*)(vto + ((size_t)b * CC + c) * NN + rowb) = pk;   // vT: 4 contiguous j
      }
    }
}

// ---------------- fused flash attention ----------------
// Block: q-rows i0..i0+127, v-channels c0..c0+127, batch b. Loop over 16 j-tiles (64).
// S fp32 in registers (C-layout), online softmax, P bf16 -> LDS (swizzled), O += P*V.
__global__ __launch_bounds__(256) void fused_attn(
    const unsigned short* __restrict__ q, const unsigned short* __restrict__ k,
    const unsigned short* __restrict__ vT, unsigned short* __restrict__ attnout) {
  __shared__ unsigned short sQ[128 * 64];   // 16 KB, staged once
  __shared__ unsigned short sK[64 * 64];    // 8 KB, per j-tile
  __shared__ unsigned short sV[128 * 64];   // 16 KB, per j-tile ([c][j])
  __shared__ unsigned short sP[128 * 64];   // 16 KB, p bf16 ([i][j])
  __shared__ float m_s[128], l_s[128], alpha_s[128];
  __shared__ float hmax[2][128], hsum[2][128];

  const int b = blockIdx.z, i0 = blockIdx.x * 128, c0 = blockIdx.y * 128;
  const int tid = threadIdx.x, wave = tid >> 6, lane = tid & 63;
  const int fm = lane & 15, kq = lane >> 4;
  const int srow = lane >> 3, sg = (lane & 7) ^ srow;

  const unsigned short* qb = q  + (size_t)b * NN * DD;
  const unsigned short* kb = k  + (size_t)b * NN * DD;
  const unsigned short* vb = vT + (size_t)b * CC * NN;

  const int srm = (wave & 1) * 64;   // S/O row base for this wave
  const int scn = (wave >> 1) * 32;  // S col base (within 64-j tile)
  const int ocn = (wave >> 1) * 64;  // O col base (c within 128-chunk)
  const int half = wave >> 1;

  if (tid < 128) { m_s[tid] = -1e30f; l_s[tid] = 0.f; }

  // stage Q once (covered by first in-loop barrier)
#pragma unroll
  for (int t = 0; t < 4; ++t) {
    const int R = wave * 32 + t * 8;
    gl_lds16(qb + (size_t)(i0 + R + srow) * DD + sg * 8, sQ + R * 64);
  }

  f32x4 O[4][4];
#pragma unroll
  for (int i = 0; i < 4; ++i)
#pragma unroll
    for (int j = 0; j < 4; ++j) O[i][j] = (f32x4)(0.0f);

  for (int jt = 0; jt < 16; ++jt) {
    const int j0 = jt * 64;
    // stage K (64 rows x 64d) and V (128 c-rows x 64j)
    {
      const int R = wave * 16;
      gl_lds16(kb + (size_t)(j0 + R + srow) * DD + sg * 8, sK + R * 64);
      gl_lds16(kb + (size_t)(j0 + R + 8 + srow) * DD + sg * 8, sK + (R + 8) * 64);
    }
#pragma unroll
    for (int t = 0; t < 4; ++t) {
      const int R = wave * 32 + t * 8;
      gl_lds16(vb + (size_t)(c0 + R + srow) * NN + j0 + sg * 8, sV + R * 64);
    }
    __syncthreads();                     // A: staging drained (Q included at jt=0)

    // ---- S = Q K^T : wave covers rows srm..+63, cols scn..+31, K=64 ----
    f32x4 S[4][2];
#pragma unroll
    for (int i = 0; i < 4; ++i) { S[i][0] = (f32x4)(0.0f); S[i][1] = (f32x4)(0.0f); }
#pragma unroll
    for (int kd = 0; kd < 2; ++kd) {
      bf16x8 aq[4], bk[2];
#pragma unroll
      for (int i = 0; i < 4; ++i) {
        const int ra = srm + i * 16 + fm;
        aq[i] = *(const bf16x8*)(sQ + ra * 64 + ((kd * 4 + kq) ^ (ra & 7)) * 8);
      }
#pragma unroll
      for (int jf = 0; jf < 2; ++jf) {
        const int rb = scn + jf * 16 + fm;
        bk[jf] = *(const bf16x8*)(sK + rb * 64 + ((kd * 4 + kq) ^ (rb & 7)) * 8);
      }
#pragma unroll
      for (int i = 0; i < 4; ++i)
#pragma unroll
        for (int jf = 0; jf < 2; ++jf)
          S[i][jf] = __builtin_amdgcn_mfma_f32_16x16x32_bf16(aq[i], bk[jf], S[i][jf], 0, 0, 0);
    }

    // ---- row max over this wave's 32 cols ----
#pragma unroll
    for (int i = 0; i < 4; ++i) {
      float mx[4];
#pragma unroll
      for (int r = 0; r < 4; ++r) {
        float m2 = fmaxf(S[i][0][r], S[i][1][r]);
#pragma unroll
        for (int off = 1; off < 16; off <<= 1) m2 = fmaxf(m2, __shfl_xor(m2, off, 64));
        mx[r] = m2;
      }
      if ((lane & 15) == 0) {
        const int rbase = srm + i * 16 + kq * 4;
#pragma unroll
        for (int r = 0; r < 4; ++r) hmax[half][rbase + r] = mx[r];
      }
    }
    __syncthreads();                     // B: hmax ready

    if (tid < 128) {
      float mo = m_s[tid];
      float mn = fmaxf(mo, fmaxf(hmax[0][tid], hmax[1][tid]));
      float a = __expf(mo - mn);
      m_s[tid] = mn; alpha_s[tid] = a; l_s[tid] *= a;
    }
    __syncthreads();                     // C: m_s/alpha_s ready

    // ---- p = exp(S-m), partial row-sums, p->sP (bf16), O *= alpha ----
    float ps[4][4];
#pragma unroll
    for (int i = 0; i < 4; ++i) {
      const int rbase = srm + i * 16 + kq * 4;
      float mrow[4], arow[4];
#pragma unroll
      for (int r = 0; r < 4; ++r) { mrow[r] = m_s[rbase + r]; arow[r] = alpha_s[rbase + r]; }
#pragma unroll
      for (int r = 0; r < 4; ++r) ps[i][r] = 0.f;
#pragma unroll
      for (int jf = 0; jf < 2; ++jf) {
        const int cj = scn + jf * 16 + fm;
#pragma unroll
        for (int r = 0; r < 4; ++r) {
          float p = __expf(S[i][jf][r] - mrow[r]);
          ps[i][r] += p;
          const int ri = rbase + r;
          sP[ri * 64 + (((cj >> 3) ^ (ri & 7)) << 3) + (cj & 7)] = bf16rn(p);
        }
      }
#pragma unroll
      for (int j = 0; j < 4; ++j)
#pragma unroll
        for (int r = 0; r < 4; ++r) O[i][j][r] *= arow[r];
    }
#pragma unroll
    for (int i = 0; i < 4; ++i) {
#pragma unroll
      for (int r = 0; r < 4; ++r) {
        float s2 = ps[i][r];
#pragma unroll
        for (int off = 1; off < 16; off <<= 1) s2 += __shfl_xor(s2, off, 64);
        ps[i][r] = s2;
      }
      if ((lane & 15) == 0) {
        const int rbase = srm + i * 16 + kq * 4;
#pragma unroll
        for (int r = 0; r < 4; ++r) hsum[half][rbase + r] = ps[i][r];
      }
    }
    __syncthreads();                     // D: sP + hsum ready

    if (tid < 128) l_s[tid] += hsum[0][tid] + hsum[1][tid];

    // ---- O += P * V : wave rows srm..+63, cols ocn..+63, K=64 ----
#pragma unroll
    for (int ks = 0; ks < 2; ++ks) {
      bf16x8 ap[4], bv[4];
#pragma unroll
      for (int i = 0; i < 4; ++i) {
        const int ra = srm + i * 16 + fm;
        ap[i] = *(const bf16x8*)(sP + ra * 64 + ((ks * 4 + kq) ^ (ra & 7)) * 8);
      }
#pragma unroll
      for (int j = 0; j < 4; ++j) {
        const int rb = ocn + j * 16 + fm;
        bv[j] = *(const bf16x8*)(sV + rb * 64 + ((ks * 4 + kq) ^ (rb & 7)) * 8);
      }
#pragma unroll
      for (int i = 0; i < 4; ++i)
#pragma unroll
        for (int j = 0; j < 4; ++j)
          O[i][j] = __builtin_amdgcn_mfma_f32_16x16x32_bf16(ap[i], bv[j], O[i][j], 0, 0, 0);
    }
    __syncthreads();                     // E: PV done, safe to restage
  }

  if (tid < 128) l_s[tid] = 1.0f / l_s[tid];
  __syncthreads();

#pragma unroll
  for (int i = 0; i < 4; ++i) {
    const int rbase = srm + i * 16 + kq * 4;
    float rv[4];
#pragma unroll
    for (int r = 0; r < 4; ++r) rv[r] = l_s[rbase + r];
#pragma unroll
    for (int j = 0; j < 4; ++j) {
      const int c = c0 + ocn + j * 16 + fm;
#pragma unroll
      for (int r = 0; r < 4; ++r)
        attnout[((size_t)b * NN + i0 + rbase + r) * CC + c] = bf16rn(O[i][j][r] * rv[r]);
    }
  }
}

// ---------------- output projection: ow[co][c] x attnout[i][c]^T -> out[b][co][i] ----------------
__global__ __launch_bounds__(256) void outproj_gemm(
    const unsigned short* __restrict__ owb, const unsigned short* __restrict__ attnout,
    const float* __restrict__ ob, float* __restrict__ out) {
  __shared__ unsigned short sA[8192], sB[8192];
  const int b = blockIdx.z, m0 = blockIdx.x * 128, n0 = blockIdx.y * 128;
  const int tid = threadIdx.x, wave = tid >> 6, lane = tid & 63;
  f32x4 acc[4][4];
#pragma unroll
  for (int i = 0; i < 4; ++i)
#pragma unroll
    for (int j = 0; j < 4; ++j) acc[i][j] = (f32x4)(0.0f);

  gemm_core<512>(owb, attnout + (size_t)b * NN * CC, m0, n0, tid, sA, sB, acc);

  const int wm = (wave & 1) * 64, wn = (wave >> 1) * 64;
#pragma unroll
  for (int i = 0; i < 4; ++i)
#pragma unroll
    for (int j = 0; j < 4; ++j) {
      int col  = n0 + wn + j * 16 + (lane & 15);      // i
      int rowb = m0 + wm + i * 16 + (lane >> 4) * 4;  // co
      f4 b4 = *(const f4*)(ob + rowb);
#pragma unroll
      for (int r = 0; r < 4; ++r)
        out[((size_t)b * CC + rowb + r) * NN + col] = acc[i][j][r] + ((const float*)&b4)[r];
    }
}

extern "C" void kernel_launch(void* const* d_in, const int* in_sizes, int n_in,
                              void* d_out, int out_size, void* d_ws, size_t ws_size,
                              hipStream_t stream) {
  const float* x   = (const float*)d_in[0];
  const float* pos = (const float*)d_in[1];
  const float* qw  = (const float*)d_in[2];
  const float* qb  = (const float*)d_in[3];
  const float* kw  = (const float*)d_in[4];
  const float* kb  = (const float*)d_in[5];
  const float* vw  = (const float*)d_in[6];
  const float* vb  = (const float*)d_in[7];
  const float* ow  = (const float*)d_in[8];
  const float* ob  = (const float*)d_in[9];
  float* out = (float*)d_out;

  // workspace layout (bytes), total ~73 MB:
  char* w = (char*)d_ws;
  unsigned short* wcat = (unsigned short*)w; w += (size_t)640 * 512 * 2;        // 0.66 MB
  unsigned short* owb  = (unsigned short*)w; w += (size_t)512 * 512 * 2;        // 0.52 MB
  float*          bcat = (float*)w;          w += 640 * 4;                      // 2.5 KB
  unsigned short* A    = (unsigned short*)w; w += (size_t)BB * NN * CC * 2;     // 32 MB (reused as attnout)
  unsigned short* q    = (unsigned short*)w; w += (size_t)BB * NN * DD * 2;     // 4 MB
  unsigned short* k    = (unsigned short*)w; w += (size_t)BB * NN * DD * 2;     // 4 MB
  unsigned short* vT   = (unsigned short*)w; w += (size_t)BB * CC * NN * 2;     // 32 MB
  unsigned short* attnout = A;  // A is dead after proj_gemm

  hipLaunchKernelGGL(prep_w, dim3(2304), dim3(256), 0, stream,
                     qw, kw, vw, qb, kb, vb, ow, wcat, owb, bcat);
  hipLaunchKernelGGL(prep_x, dim3(16, 8, 32), dim3(256), 0, stream, x, pos, A);
  hipLaunchKernelGGL(proj_gemm, dim3(8, 5, 32), dim3(256), 0, stream,
                     A, wcat, bcat, q, k, vT);
  hipLaunchKernelGGL(fused_attn, dim3(8, 4, 32), dim3(256), 0, stream,
                     q, k, vT, attnout);
  hipLaunchKernelGGL(outproj_gemm, dim3(4, 8, 32), dim3(256), 0, stream,
                     owb, attnout, ob, out);
}

// Round 6
// 323.602 us; speedup vs baseline: 1.4859x; 1.4859x over previous
//
#include <hip/hip_runtime.h>

// SpatialAttention: B=32, C=512, D=64, N=1024 (H=W=32)
#define BB 32
#define CC 512
#define DD 64
#define NN 1024
#define GRP 16                // batches per P-buffer group
#define NGRP (BB / GRP)       // 2 groups

typedef float4 f4;
typedef __attribute__((ext_vector_type(8))) short bf16x8;     // 8 bf16 = 4 VGPRs (MFMA A/B frag)
typedef __attribute__((ext_vector_type(4))) float f32x4;      // MFMA C/D frag
typedef __attribute__((ext_vector_type(4))) unsigned short us4;
typedef __attribute__((ext_vector_type(8))) unsigned short us8;

__device__ inline unsigned short bf16rn(float f) {
  union { float f; unsigned u; } v; v.f = f;
  unsigned r = v.u + 0x7fff + ((v.u >> 16) & 1);   // round-to-nearest-even
  return (unsigned short)(r >> 16);
}

__device__ inline void gl_lds16(const void* g, void* l) {
  // async global->LDS, 16B/lane; LDS dest = wave-uniform base + lane*16
  __builtin_amdgcn_global_load_lds(
      (const __attribute__((address_space(1))) unsigned int*)g,
      (__attribute__((address_space(3))) unsigned int*)l, 16, 0, 0);
}

// ---- shared GEMM core: C[128m x 128n] += A[M][K] * Bt[N][K]^T, bf16, BK=64 ----
// LDS tiles: 128 rows x 64 k-elems, XOR-swizzled: slot s of row r holds global
// k-group (s ^ (r&7)); 16B groups. Conflict-free (verified r4: SQ_LDS_BANK_CONFLICT=0).
template <int KDIM>
__device__ inline void gemm_core(const unsigned short* __restrict__ A,
                                 const unsigned short* __restrict__ Bt,
                                 int m0, int n0, int tid,
                                 unsigned short* sA, unsigned short* sB,
                                 f32x4 acc[4][4]) {
  const int wave = tid >> 6, lane = tid & 63;
  const int wm = (wave & 1) * 64, wn = (wave >> 1) * 64;
  const int fm = lane & 15;           // fragment row (m or n)
  const int kq = lane >> 4;           // fragment k-group (0..3) within 32-k window
  const int srow = lane >> 3;         // staging: row within 8-row slab (0..7)
  const int sg   = (lane & 7) ^ srow; // staging: global k-group (swizzled)

  for (int k0 = 0; k0 < KDIM; k0 += 64) {
#pragma unroll
    for (int t = 0; t < 4; ++t) {
      const int R = wave * 32 + t * 8;     // row base of this 8-row slab
      gl_lds16(A  + (size_t)(m0 + R + srow) * KDIM + k0 + sg * 8, sA + R * 64);
      gl_lds16(Bt + (size_t)(n0 + R + srow) * KDIM + k0 + sg * 8, sB + R * 64);
    }
    __syncthreads();
#pragma unroll
    for (int ks = 0; ks < 2; ++ks) {
      bf16x8 af[4], bfr[4];
#pragma unroll
      for (int i = 0; i < 4; ++i) {
        const int ra = wm + i * 16 + fm;
        const int rb = wn + i * 16 + fm;
        af[i]  = *(const bf16x8*)(sA + ra * 64 + ((ks * 4 + kq) ^ (ra & 7)) * 8);
        bfr[i] = *(const bf16x8*)(sB + rb * 64 + ((ks * 4 + kq) ^ (rb & 7)) * 8);
      }
#pragma unroll
      for (int i = 0; i < 4; ++i)
#pragma unroll
        for (int j = 0; j < 4; ++j)
          acc[i][j] = __builtin_amdgcn_mfma_f32_16x16x32_bf16(af[i], bfr[j], acc[i][j], 0, 0, 0);
    }
    __syncthreads();
  }
}

// ---------------- prep: weights -> bf16 ----------------
__global__ __launch_bounds__(256) void prep_w(
    const float* __restrict__ qw, const float* __restrict__ kw, const float* __restrict__ vw,
    const float* __restrict__ qb, const float* __restrict__ kb, const float* __restrict__ vb,
    const float* __restrict__ ow,
    unsigned short* __restrict__ wcat, unsigned short* __restrict__ owb,
    float* __restrict__ bcat) {
  int idx = blockIdx.x * 256 + threadIdx.x;
  if (idx < 640 * 512) {
    int row = idx >> 9;
    float v = (row < 64) ? qw[idx] : (row < 128) ? kw[idx - 64 * 512] : vw[idx - 128 * 512];
    wcat[idx] = bf16rn(v);
    if (idx < 640) bcat[idx] = (idx < 64) ? qb[idx] : (idx < 128) ? kb[idx - 64] : vb[idx - 128];
  } else {
    int j = idx - 640 * 512;
    owb[j] = bf16rn(ow[j]);
  }
}

// ---------------- prep: A[b][i][c] = bf16(x[b][c][i] + pos[c][i]) ----------------
__global__ __launch_bounds__(256) void prep_x(const float* __restrict__ x,
                                              const float* __restrict__ pos,
                                              unsigned short* __restrict__ A) {
  __shared__ float t[64][65];
  const int b = blockIdx.z, i0 = blockIdx.x * 64, c0 = blockIdx.y * 64;
  const int tid = threadIdx.x;
  const int ci = tid >> 4, il = (tid & 15) * 4;
  const float* xb = x + (size_t)b * CC * NN;
#pragma unroll
  for (int r = 0; r < 4; ++r) {
    int cl = r * 16 + ci;
    f4 xv = *(const f4*)(xb  + (size_t)(c0 + cl) * NN + i0 + il);
    f4 pv = *(const f4*)(pos + (size_t)(c0 + cl) * NN + i0 + il);
    t[cl][il + 0] = xv.x + pv.x;
    t[cl][il + 1] = xv.y + pv.y;
    t[cl][il + 2] = xv.z + pv.z;
    t[cl][il + 3] = xv.w + pv.w;
  }
  __syncthreads();
  const int iw = tid >> 2, cw = (tid & 3) * 16;
  unsigned short* dst = A + ((size_t)b * NN + i0 + iw) * CC + c0 + cw;
  us8 p0, p1;
#pragma unroll
  for (int j = 0; j < 8; ++j) p0[j] = bf16rn(t[cw + j][iw]);
#pragma unroll
  for (int j = 0; j < 8; ++j) p1[j] = bf16rn(t[cw + 8 + j][iw]);
  *(us8*)dst = p0;
  *(us8*)(dst + 8) = p1;
}

// ---------------- QKV projection GEMM ----------------
__global__ __launch_bounds__(256) void proj_gemm(
    const unsigned short* __restrict__ A, const unsigned short* __restrict__ wcat,
    const float* __restrict__ bcat,
    unsigned short* __restrict__ qo, unsigned short* __restrict__ ko,
    unsigned short* __restrict__ vto) {
  __shared__ unsigned short sA[8192], sB[8192];
  const int b = blockIdx.z, m0 = blockIdx.x * 128, n0 = blockIdx.y * 128;
  const int tid = threadIdx.x, wave = tid >> 6, lane = tid & 63;
  f32x4 acc[4][4];
#pragma unroll
  for (int i = 0; i < 4; ++i)
#pragma unroll
    for (int j = 0; j < 4; ++j) acc[i][j] = (f32x4)(0.0f);

  gemm_core<512>(A + (size_t)b * NN * CC, wcat, m0, n0, tid, sA, sB, acc);

  const int wm = (wave & 1) * 64, wn = (wave >> 1) * 64;
#pragma unroll
  for (int i = 0; i < 4; ++i)
#pragma unroll
    for (int j = 0; j < 4; ++j) {
      int col  = n0 + wn + j * 16 + (lane & 15);
      int rowb = m0 + wm + i * 16 + (lane >> 4) * 4;
      float bias = bcat[col];
      if (col < 64) {
#pragma unroll
        for (int r = 0; r < 4; ++r)
          qo[((size_t)b * NN + rowb + r) * DD + col] = bf16rn(acc[i][j][r] + bias);
      } else if (col < 128) {
#pragma unroll
        for (int r = 0; r < 4; ++r)
          ko[((size_t)b * NN + rowb + r) * DD + col - 64] = bf16rn(acc[i][j][r] + bias);
      } else {
        int c = col - 128;
        us4 pk;
#pragma unroll
        for (int r = 0; r < 4; ++r) pk[r] = bf16rn(acc[i][j][r] + bias);
        *(us4*)(vto + ((size_t)b * CC + c) * NN + rowb) = pk;   // vT: 4 contiguous j
      }
    }
}

// ---------------- pass 1: softmax stats (m, l) per row, no scores stored ----------------
// Block: 128 q-rows x batch. Loop 8 K-tiles of 128, S in registers, online (m,l).
__global__ __launch_bounds__(256) void stats_kernel(
    const unsigned short* __restrict__ q, const unsigned short* __restrict__ k,
    float2* __restrict__ stats) {
  __shared__ unsigned short sQ[128 * 64];   // 16 KB
  __shared__ unsigned short sK[128 * 64];   // 16 KB
  __shared__ float2 wred[4][128];           // 4 KB

  const int b = blockIdx.y, i0 = blockIdx.x * 128;
  const int tid = threadIdx.x, wave = tid >> 6, lane = tid & 63;
  const int wm = (wave & 1) * 64, wn = (wave >> 1) * 64;
  const int fm = lane & 15, kq = lane >> 4;
  const int srow = lane >> 3, sg = (lane & 7) ^ srow;

  const unsigned short* qb = q + (size_t)b * NN * DD;
  const unsigned short* kb = k + (size_t)b * NN * DD;

  // stage Q once
#pragma unroll
  for (int t = 0; t < 4; ++t) {
    const int R = wave * 32 + t * 8;
    gl_lds16(qb + (size_t)(i0 + R + srow) * DD + sg * 8, sQ + R * 64);
  }

  bf16x8 aq[4][2];
  float m_l[4][4], l_l[4][4];
#pragma unroll
  for (int i = 0; i < 4; ++i)
#pragma unroll
    for (int r = 0; r < 4; ++r) { m_l[i][r] = -1e30f; l_l[i][r] = 0.f; }

  for (int jt = 0; jt < 8; ++jt) {
    const int j0 = jt * 128;
#pragma unroll
    for (int t = 0; t < 4; ++t) {
      const int R = wave * 32 + t * 8;
      gl_lds16(kb + (size_t)(j0 + R + srow) * DD + sg * 8, sK + R * 64);
    }
    __syncthreads();             // staging drained (Q included at jt=0)
    if (jt == 0) {
#pragma unroll
      for (int i = 0; i < 4; ++i)
#pragma unroll
        for (int kd = 0; kd < 2; ++kd) {
          const int ra = wm + i * 16 + fm;
          aq[i][kd] = *(const bf16x8*)(sQ + ra * 64 + ((kd * 4 + kq) ^ (ra & 7)) * 8);
        }
    }
    f32x4 S[4][4];
#pragma unroll
    for (int i = 0; i < 4; ++i)
#pragma unroll
      for (int j = 0; j < 4; ++j) S[i][j] = (f32x4)(0.0f);
#pragma unroll
    for (int kd = 0; kd < 2; ++kd) {
      bf16x8 bk[4];
#pragma unroll
      for (int j = 0; j < 4; ++j) {
        const int rb = wn + j * 16 + fm;
        bk[j] = *(const bf16x8*)(sK + rb * 64 + ((kd * 4 + kq) ^ (rb & 7)) * 8);
      }
#pragma unroll
      for (int i = 0; i < 4; ++i)
#pragma unroll
        for (int j = 0; j < 4; ++j)
          S[i][j] = __builtin_amdgcn_mfma_f32_16x16x32_bf16(aq[i][kd], bk[j], S[i][j], 0, 0, 0);
    }
    // online update per (i,r) with this tile's 4 values
#pragma unroll
    for (int i = 0; i < 4; ++i)
#pragma unroll
      for (int r = 0; r < 4; ++r) {
        float v0 = S[0 * 0 + i][0][r], v1 = S[i][1][r], v2 = S[i][2][r], v3 = S[i][3][r];
        float mt = fmaxf(fmaxf(v0, v1), fmaxf(v2, v3));
        float lt = __expf(v0 - mt) + __expf(v1 - mt) + __expf(v2 - mt) + __expf(v3 - mt);
        float mo = m_l[i][r];
        float mn = fmaxf(mo, mt);
        l_l[i][r] = l_l[i][r] * __expf(mo - mn) + lt * __expf(mt - mn);
        m_l[i][r] = mn;
      }
    __syncthreads();             // protect sK before restage
  }

  // reduce across the 16 fm-lanes (same kq quad)
#pragma unroll
  for (int i = 0; i < 4; ++i)
#pragma unroll
    for (int r = 0; r < 4; ++r) {
      float m = m_l[i][r], l = l_l[i][r];
#pragma unroll
      for (int off = 1; off < 16; off <<= 1) {
        float mo = __shfl_xor(m, off, 64);
        float lo = __shfl_xor(l, off, 64);
        float mn = fmaxf(m, mo);
        l = l * __expf(m - mn) + lo * __expf(mo - mn);
        m = mn;
      }
      m_l[i][r] = m; l_l[i][r] = l;
    }
  if ((lane & 15) == 0) {
#pragma unroll
    for (int i = 0; i < 4; ++i)
#pragma unroll
      for (int r = 0; r < 4; ++r) {
        float2 p; p.x = m_l[i][r]; p.y = l_l[i][r];
        wred[wave][wm + i * 16 + kq * 4 + r] = p;
      }
  }
  __syncthreads();
  if (tid < 128) {
    const int a = tid >> 6;                 // rows 0-63 -> waves 0,2; 64-127 -> 1,3
    float2 p0 = wred[a][tid], p1 = wred[a + 2][tid];
    float mn = fmaxf(p0.x, p1.x);
    float l = p0.y * __expf(p0.x - mn) + p1.y * __expf(p1.x - mn);
    float2 o; o.x = mn; o.y = l;
    stats[(size_t)b * NN + i0 + tid] = o;
  }
}

// ---------------- pass 2: recompute S, write normalized P bf16 ----------------
__global__ __launch_bounds__(256) void pnorm_kernel(
    const unsigned short* __restrict__ q, const unsigned short* __restrict__ k,
    const float2* __restrict__ stats, unsigned short* __restrict__ P) {
  __shared__ unsigned short sQ[128 * 64];
  __shared__ unsigned short sK[128 * 64];

  const int b = blockIdx.y, i0 = blockIdx.x * 128;   // b is group-local
  const int tid = threadIdx.x, wave = tid >> 6, lane = tid & 63;
  const int wm = (wave & 1) * 64, wn = (wave >> 1) * 64;
  const int fm = lane & 15, kq = lane >> 4;
  const int srow = lane >> 3, sg = (lane & 7) ^ srow;

  const unsigned short* qb = q + (size_t)b * NN * DD;
  const unsigned short* kb = k + (size_t)b * NN * DD;

#pragma unroll
  for (int t = 0; t < 4; ++t) {
    const int R = wave * 32 + t * 8;
    gl_lds16(qb + (size_t)(i0 + R + srow) * DD + sg * 8, sQ + R * 64);
  }

  float mrow[4][4], irow[4][4];
#pragma unroll
  for (int i = 0; i < 4; ++i)
#pragma unroll
    for (int r = 0; r < 4; ++r) {
      float2 st = stats[(size_t)b * NN + i0 + wm + i * 16 + kq * 4 + r];
      mrow[i][r] = st.x; irow[i][r] = 1.0f / st.y;
    }

  bf16x8 aq[4][2];
  for (int jt = 0; jt < 8; ++jt) {
    const int j0 = jt * 128;
#pragma unroll
    for (int t = 0; t < 4; ++t) {
      const int R = wave * 32 + t * 8;
      gl_lds16(kb + (size_t)(j0 + R + srow) * DD + sg * 8, sK + R * 64);
    }
    __syncthreads();
    if (jt == 0) {
#pragma unroll
      for (int i = 0; i < 4; ++i)
#pragma unroll
        for (int kd = 0; kd < 2; ++kd) {
          const int ra = wm + i * 16 + fm;
          aq[i][kd] = *(const bf16x8*)(sQ + ra * 64 + ((kd * 4 + kq) ^ (ra & 7)) * 8);
        }
    }
    f32x4 S[4][4];
#pragma unroll
    for (int i = 0; i < 4; ++i)
#pragma unroll
      for (int j = 0; j < 4; ++j) S[i][j] = (f32x4)(0.0f);
#pragma unroll
    for (int kd = 0; kd < 2; ++kd) {
      bf16x8 bk[4];
#pragma unroll
      for (int j = 0; j < 4; ++j) {
        const int rb = wn + j * 16 + fm;
        bk[j] = *(const bf16x8*)(sK + rb * 64 + ((kd * 4 + kq) ^ (rb & 7)) * 8);
      }
#pragma unroll
      for (int i = 0; i < 4; ++i)
#pragma unroll
        for (int j = 0; j < 4; ++j)
          S[i][j] = __builtin_amdgcn_mfma_f32_16x16x32_bf16(aq[i][kd], bk[j], S[i][j], 0, 0, 0);
    }
#pragma unroll
    for (int i = 0; i < 4; ++i)
#pragma unroll
      for (int j = 0; j < 4; ++j) {
        const int col = j0 + wn + j * 16 + fm;
#pragma unroll
        for (int r = 0; r < 4; ++r) {
          const int row = i0 + wm + i * 16 + kq * 4 + r;
          P[((size_t)b * NN + row) * NN + col] =
              bf16rn(__expf(S[i][j][r] - mrow[i][r]) * irow[i][r]);
        }
      }
    __syncthreads();
  }
}

// ---------------- PV GEMM: P[b'] x vT[b']^T -> attnout bf16 [b'][i][c] ----------------
__global__ __launch_bounds__(256) void pv_gemm(
    const unsigned short* __restrict__ P, const unsigned short* __restrict__ vT,
    unsigned short* __restrict__ attnout) {
  __shared__ unsigned short sA[8192], sB[8192];
  const int b = blockIdx.z, m0 = blockIdx.x * 128, n0 = blockIdx.y * 128;
  const int tid = threadIdx.x, wave = tid >> 6, lane = tid & 63;
  f32x4 acc[4][4];
#pragma unroll
  for (int i = 0; i < 4; ++i)
#pragma unroll
    for (int j = 0; j < 4; ++j) acc[i][j] = (f32x4)(0.0f);

  gemm_core<1024>(P + (size_t)b * NN * NN, vT + (size_t)b * CC * NN, m0, n0, tid, sA, sB, acc);

  const int wm = (wave & 1) * 64, wn = (wave >> 1) * 64;
#pragma unroll
  for (int i = 0; i < 4; ++i)
#pragma unroll
    for (int j = 0; j < 4; ++j) {
      int col  = n0 + wn + j * 16 + (lane & 15);
      int rowb = m0 + wm + i * 16 + (lane >> 4) * 4;
#pragma unroll
      for (int r = 0; r < 4; ++r)
        attnout[((size_t)b * NN + rowb + r) * CC + col] = bf16rn(acc[i][j][r]);
    }
}

// ---------------- output projection: ow[co][c] x attnout[i][c]^T -> out[b][co][i] ----------------
__global__ __launch_bounds__(256) void outproj_gemm(
    const unsigned short* __restrict__ owb, const unsigned short* __restrict__ attnout,
    const float* __restrict__ ob, float* __restrict__ out) {
  __shared__ unsigned short sA[8192], sB[8192];
  const int b = blockIdx.z, m0 = blockIdx.x * 128, n0 = blockIdx.y * 128;
  const int tid = threadIdx.x, wave = tid >> 6, lane = tid & 63;
  f32x4 acc[4][4];
#pragma unroll
  for (int i = 0; i < 4; ++i)
#pragma unroll
    for (int j = 0; j < 4; ++j) acc[i][j] = (f32x4)(0.0f);

  gemm_core<512>(owb, attnout + (size_t)b * NN * CC, m0, n0, tid, sA, sB, acc);

  const int wm = (wave & 1) * 64, wn = (wave >> 1) * 64;
#pragma unroll
  for (int i = 0; i < 4; ++i)
#pragma unroll
    for (int j = 0; j < 4; ++j) {
      int col  = n0 + wn + j * 16 + (lane & 15);      // i
      int rowb = m0 + wm + i * 16 + (lane >> 4) * 4;  // co
      f4 b4 = *(const f4*)(ob + rowb);
#pragma unroll
      for (int r = 0; r < 4; ++r)
        out[((size_t)b * CC + rowb + r) * NN + col] = acc[i][j][r] + ((const float*)&b4)[r];
    }
}

extern "C" void kernel_launch(void* const* d_in, const int* in_sizes, int n_in,
                              void* d_out, int out_size, void* d_ws, size_t ws_size,
                              hipStream_t stream) {
  const float* x   = (const float*)d_in[0];
  const float* pos = (const float*)d_in[1];
  const float* qw  = (const float*)d_in[2];
  const float* qb  = (const float*)d_in[3];
  const float* kw  = (const float*)d_in[4];
  const float* kb  = (const float*)d_in[5];
  const float* vw  = (const float*)d_in[6];
  const float* vb  = (const float*)d_in[7];
  const float* ow  = (const float*)d_in[8];
  const float* ob  = (const float*)d_in[9];
  float* out = (float*)d_out;

  // workspace layout (bytes), total ~106 MB (121 MB known-good; 265 MB crashed):
  char* w = (char*)d_ws;
  unsigned short* wcat = (unsigned short*)w; w += (size_t)640 * 512 * 2;        // 0.66 MB
  unsigned short* owb  = (unsigned short*)w; w += (size_t)512 * 512 * 2;        // 0.52 MB
  float*          bcat = (float*)w;          w += 640 * 4;                      // 2.5 KB
  unsigned short* A    = (unsigned short*)w; w += (size_t)BB * NN * CC * 2;     // 32 MB (reused as attnout)
  unsigned short* q    = (unsigned short*)w; w += (size_t)BB * NN * DD * 2;     // 4 MB
  unsigned short* k    = (unsigned short*)w; w += (size_t)BB * NN * DD * 2;     // 4 MB
  unsigned short* vT   = (unsigned short*)w; w += (size_t)BB * CC * NN * 2;     // 32 MB
  float2*        stats = (float2*)w;         w += (size_t)BB * NN * 8;          // 0.25 MB
  unsigned short* PG   = (unsigned short*)w; w += (size_t)GRP * NN * NN * 2;    // 32 MB (per-group)
  unsigned short* attnout = A;  // A is dead after proj_gemm

  hipLaunchKernelGGL(prep_w, dim3(2304), dim3(256), 0, stream,
                     qw, kw, vw, qb, kb, vb, ow, wcat, owb, bcat);
  hipLaunchKernelGGL(prep_x, dim3(16, 8, 32), dim3(256), 0, stream, x, pos, A);
  hipLaunchKernelGGL(proj_gemm, dim3(8, 5, 32), dim3(256), 0, stream,
                     A, wcat, bcat, q, k, vT);
  hipLaunchKernelGGL(stats_kernel, dim3(8, 32), dim3(256), 0, stream, q, k, stats);

  for (int g = 0; g < NGRP; ++g) {
    const unsigned short* qg  = q  + (size_t)g * GRP * NN * DD;
    const unsigned short* kg  = k  + (size_t)g * GRP * NN * DD;
    const unsigned short* vTg = vT + (size_t)g * GRP * CC * NN;
    const float2*         stg = stats + (size_t)g * GRP * NN;
    unsigned short* aog = attnout + (size_t)g * GRP * NN * CC;
    hipLaunchKernelGGL(pnorm_kernel, dim3(8, GRP), dim3(256), 0, stream, qg, kg, stg, PG);
    hipLaunchKernelGGL(pv_gemm, dim3(8, 4, GRP), dim3(256), 0, stream, PG, vTg, aog);
  }

  hipLaunchKernelGGL(outproj_gemm, dim3(4, 8, 32), dim3(256), 0, stream,
                     owb, attnout, ob, out);
}